// Round 4
// baseline (2980.421 us; speedup 1.0000x reference)
//
#include <hip/hip_runtime.h>
#include <math.h>

#define T_TOTAL   1000
#define BATCH     256
#define NH        256
#define NIN       85

static constexpr float SIGMA_C = 0.15811388300841897f;  // sqrt(2/0.2)*0.05
static constexpr float ALPHA_C = 0.2f;

using half8   = __attribute__((ext_vector_type(8))) _Float16;
using f32x4   = __attribute__((ext_vector_type(4))) float;

// workspace layout
#define GXE_F     ((size_t)(T_TOTAL+1)*16*48*256)   // f32 gxe: [t][R][tau(48)][lane(64)][4] = 789MB
#define WPACK_US  (8u*6u*8u*64u*8u)                 // recurrent-weight B-fragments (f16 bits)
#define WXPACK_US (48u*3u*64u*8u)                   // x-weight B-fragments (K padded 85->96)

__device__ __forceinline__ unsigned short f2h(float f){
  _Float16 h = (_Float16)f;
  return __builtin_bit_cast(unsigned short, h);
}

__device__ __forceinline__ void gload_lds16(const void* g, void* l){
  __builtin_amdgcn_global_load_lds((const __attribute__((address_space(1))) void*)g,
                                   (__attribute__((address_space(3))) void*)l, 16, 0, 0);
}

// ---------------- k0: pack weights into MFMA B-fragment order (f16) ----------------
__global__ void k0_pack(const float* __restrict__ gk, const float* __restrict__ ck,
                        unsigned short* __restrict__ wpack, unsigned short* __restrict__ wxpack){
  int tid = blockIdx.x*256 + threadIdx.x;
  if (tid < (int)WPACK_US) {
    int j = tid & 7, l = (tid >> 3) & 63, kt = (tid >> 9) & 7, wt = tid >> 12;
    int w = wt / 6, tile = wt - 6*w;
    int lrow = l & 15, lquad = l >> 4;
    int k = kt*32 + lquad*8 + j;            // hidden index 0..255
    int tau = 2*w + (tile & 1);             // n-tile 0..15
    int kind = tile >> 1;                   // 0=r, 1=u, 2=c
    float v;
    if (kind == 0)      v = gk[(size_t)(85 + k)*512 + 16*tau + lrow];
    else if (kind == 1) v = gk[(size_t)(85 + k)*512 + 256 + 16*tau + lrow];
    else                v = ck[(size_t)(85 + k)*256 + 16*tau + lrow];
    wpack[tid] = f2h(v);
  } else if (tid < (int)(WPACK_US + WXPACK_US)) {
    int f = tid - (int)WPACK_US;
    int j = f & 7, l = (f >> 3) & 63, r = f >> 9;   // r = tau*3 + kt
    int kt = r % 3, tau = r / 3;
    int lrow = l & 15, lquad = l >> 4;
    int k = kt*32 + lquad*8 + j;            // x index, pad >=85 -> 0
    float v = 0.0f;
    if (k < NIN) {
      if (tau < 32) v = gk[(size_t)k*512 + 16*tau + lrow];
      else          v = ck[(size_t)k*256 + 16*(tau-32) + lrow];
    }
    wxpack[f] = f2h(v);
  }
}

// ---------------- k1: gxe precompute, ONE dispatch over all T ----------------
// gxe[t][R][tau(48)][lane(64)][i(4)] f32, C-fragment order:
//   tau<32 : gate preact x-part (incl gate_bias); tau>=32: E = cand_bias + cx + sigma*noise
__global__ __launch_bounds__(256) void k1_gxe(const float* __restrict__ x, const float* __restrict__ nz,
                       const float* __restrict__ gb, const float* __restrict__ cb,
                       const unsigned short* __restrict__ wxpack, float* __restrict__ gxe){
  int R  = blockIdx.x;
  int t  = blockIdx.y;
  int tid = threadIdx.x;
  __shared__ _Float16 xA[16][104];           // 96 K (padded) + 8 pad
  {
    int r = tid >> 4, c0 = tid & 15;
    const float* xrow = x + ((size_t)t*BATCH + 16*R + r)*NIN;
    for (int c = c0; c < 96; c += 16)
      xA[r][c] = (_Float16)(c < NIN ? xrow[c] : 0.0f);
  }
  __syncthreads();
  int l = tid & 63, wv = tid >> 6;
  int lrow = l & 15, lquad = l >> 4;
  const half8* xA8 = (const half8*)xA;       // row stride 104 f16 = 13 half8
  half8 afr[3];
  #pragma unroll
  for (int kt = 0; kt < 3; ++kt)
    afr[kt] = xA8[lrow*13 + kt*4 + lquad];
  const half8* wx8 = (const half8*)wxpack;
  size_t gbase = ((size_t)t*16 + R)*48;
  for (int u = 0; u < 12; ++u) {
    int tau = wv + 4*u;                      // balanced: each wave gets 4 cand tiles
    f32x4 acc;
    if (tau < 32) {
      float b = gb[16*tau + lrow];
      acc = (f32x4){b, b, b, b};
    } else {
      int nc = 16*(tau-32) + lrow;
      float b = cb[nc];
      #pragma unroll
      for (int i = 0; i < 4; ++i)
        acc[i] = fmaf(SIGMA_C, nz[((size_t)t*BATCH + 16*R + lquad*4 + i)*NH + nc], b);
    }
    #pragma unroll
    for (int kt = 0; kt < 3; ++kt)
      acc = __builtin_amdgcn_mfma_f32_16x16x32_f16(afr[kt], wx8[((size_t)tau*3 + kt)*64 + l], acc, 0, 0, 0);
    *(f32x4*)(gxe + ((gbase + tau)*64 + (size_t)l)*4) = acc;
  }
}

// ---------------- k2: ONE persistent recurrent scan over all 1000 steps ----------------
// 16 WGs x 8 waves. WG R owns batch rows [16R,16R+16); wave w owns n-cols [32w,32w+32).
// cand = cx + (r .* h) @ Wc_h + sigma*n  (r applied BEFORE the matmul).
// Sync design (NO __syncthreads in loop — avoids vmcnt(0) store drains):
//   - 2x  "s_waitcnt lgkmcnt(0); s_barrier" per step (rhA publish, hA publish).
//   - gate DMA (wave-private gst) guarded by counted "s_waitcnt vmcnt(10)":
//     exactly 10 VMEM ops (8 out stores + 2 E loads) are issued after the 4 DMAs.
//   - gst is read ONLY via inline asm, so the compiler inserts no vmcnt for it.
__global__ __launch_bounds__(512, 2) void k2_rec(const float* __restrict__ hin,
                       const unsigned short* __restrict__ wpack,
                       const float* __restrict__ gxe,
                       float* __restrict__ out){
  int R = blockIdx.x;
  int tid = threadIdx.x;
  int l = tid & 63, w = tid >> 6;
  int lrow = l & 15, lquad = l >> 4;

  __shared__ float    gst[8*4*256];          // [w][gate tile q(4)][lane][4] f32, 32KB (DMA dest)
  __shared__ _Float16 hA[16][264];           // h f16  [row][n], stride 264
  __shared__ _Float16 rhA[16][264];          // r.*h f16, same layout

  { // init hA
    int r = tid >> 5, c0 = (tid & 31)*8;
    const float* hrow = hin + ((size_t)(16*R + r))*NH + c0;
    #pragma unroll
    for (int i = 0; i < 8; ++i)
      hA[r][c0+i] = (_Float16)hrow[i];
  }
  float hreg[2][4];                          // h f32, lane-private (rows lquad*4+i, cols 32w+16p+lrow)
  #pragma unroll
  for (int p = 0; p < 2; ++p)
    #pragma unroll
    for (int i = 0; i < 4; ++i)
      hreg[p][i] = hin[(size_t)(16*R + lquad*4 + i)*NH + 32*w + 16*p + lrow];

  // resident weight fragments (192 VGPRs)
  half8 wf[6][8];
  const half8* wp8 = (const half8*)wpack;
  #pragma unroll
  for (int tile = 0; tile < 6; ++tile)
    #pragma unroll
    for (int kt = 0; kt < 8; ++kt)
      wf[tile][kt] = wp8[((w*6 + tile)*8 + kt)*64 + l];

  // gate staging: tile q -> tau = 2w + {0,1,16,17}; E tiles tau = 32+2w, 33+2w
  const size_t gstep  = (size_t)16*48*256;   // floats per time step
  const float* gsrc   = gxe + ((size_t)R*48 + 2*w)*256 + (size_t)l*4;   // per-lane DMA src
  const f32x4* gep    = (const f32x4*)gxe + ((size_t)R*48 + 32 + 2*w)*64 + (size_t)l;
  float* lbase = gst + (size_t)w*4*256;                                  // wave-uniform LDS dest
  unsigned sb_addr = (unsigned)(unsigned long long)(const void*)lbase + (unsigned)l*16u;

  // prologue: stage step-0 gates, load E(0); __syncthreads drains everything once
  gload_lds16(gsrc,             lbase);
  gload_lds16(gsrc +  1*256,    lbase + 1*256);
  gload_lds16(gsrc + 16*256,    lbase + 2*256);
  gload_lds16(gsrc + 17*256,    lbase + 3*256);
  f32x4 e0 = gep[0];
  f32x4 e1 = gep[64];
  __syncthreads();

  const half8* hA8  = (const half8*)hA;      // row stride 33 half8
  const half8* rhA8 = (const half8*)rhA;
  float* outp = out + ((size_t)(16*R + lquad*4))*NH + 32*w + lrow;

  for (int t = 0; t < T_TOTAL; ++t) {
    // gate preacts: wait own DMA (counted), read gst, data in regs (asm-only access)
    f32x4 accA[4];
    asm volatile(
      "s_waitcnt vmcnt(10)\n\t"
      "ds_read_b128 %0, %4\n\t"
      "ds_read_b128 %1, %4 offset:1024\n\t"
      "ds_read_b128 %2, %4 offset:2048\n\t"
      "ds_read_b128 %3, %4 offset:3072\n\t"
      "s_waitcnt lgkmcnt(0)"
      : "=&v"(accA[0]), "=&v"(accA[1]), "=&v"(accA[2]), "=&v"(accA[3])
      : "v"(sb_addr) : "memory");
    // stage gates(t+1) into the same wave-private slots
    if (t != T_TOTAL-1) {
      const float* gs = gsrc + gstep;
      gload_lds16(gs,          lbase);
      gload_lds16(gs +  1*256, lbase + 1*256);
      gload_lds16(gs + 16*256, lbase + 2*256);
      gload_lds16(gs + 17*256, lbase + 3*256);
    }
    gsrc += gstep;
    // phase A: h @ Wg_h  (tiles r0,r1,u0,u1)
    #pragma unroll
    for (int kt = 0; kt < 8; ++kt){
      half8 af = hA8[lrow*33 + kt*4 + lquad];
      #pragma unroll
      for (int tile = 0; tile < 4; ++tile)
        accA[tile] = __builtin_amdgcn_mfma_f32_16x16x32_f16(af, wf[tile][kt], accA[tile], 0, 0, 0);
    }
    // ew1: gates; publish rh = r .* h
    float aug[2][4];
    #pragma unroll
    for (int p = 0; p < 2; ++p){
      int ncol = 32*w + 16*p + lrow;
      #pragma unroll
      for (int i = 0; i < 4; ++i){
        float er = __expf(-accA[p][i]);
        float rg = __builtin_amdgcn_rcpf(1.0f + er);
        float eu = __expf(-accA[2+p][i]);
        aug[p][i] = ALPHA_C * __builtin_amdgcn_rcpf(1.0f + eu);
        rhA[lquad*4+i][ncol] = (_Float16)(rg * hreg[p][i]);
      }
    }
    asm volatile("s_waitcnt lgkmcnt(0)\n\ts_barrier" ::: "memory");  // rhA visible
    // phase B: (r.*h) @ Wc_h  (tiles c0,c1)
    f32x4 accB[2];
    accB[0] = (f32x4){0.f,0.f,0.f,0.f};
    accB[1] = (f32x4){0.f,0.f,0.f,0.f};
    #pragma unroll
    for (int kt = 0; kt < 8; ++kt){
      half8 af = rhA8[lrow*33 + kt*4 + lquad];
      #pragma unroll
      for (int tile = 0; tile < 2; ++tile)
        accB[tile] = __builtin_amdgcn_mfma_f32_16x16x32_f16(af, wf[4+tile][kt], accB[tile], 0, 0, 0);
    }
    // ew2: cand -> tanh -> leaky update; publish new h; 8 out stores (never drained)
    #pragma unroll
    for (int p = 0; p < 2; ++p){
      const f32x4 e = p ? e1 : e0;
      int ncol = 32*w + 16*p + lrow;
      #pragma unroll
      for (int i = 0; i < 4; ++i){
        float cand = accB[p][i] + e[i];
        float e2 = __expf(2.0f*cand);
        float c  = (e2 - 1.0f)*__builtin_amdgcn_rcpf(e2 + 1.0f);
        float hold = hreg[p][i];
        float hnew = fmaf(aug[p][i], c - hold, hold);
        hreg[p][i] = hnew;
        hA[lquad*4+i][ncol] = (_Float16)hnew;
        outp[(size_t)i*NH + (size_t)p*16] = hnew;
      }
    }
    outp += (size_t)BATCH*NH;
    // E(t+1) into regs (after last use of e0/e1; part of the vmcnt(10) count)
    gep += gstep/4;
    e0 = gep[0];
    e1 = gep[64];
    asm volatile("s_waitcnt lgkmcnt(0)\n\ts_barrier" ::: "memory");  // hA visible
  }
}

extern "C" void kernel_launch(void* const* d_in, const int* in_sizes, int n_in,
                              void* d_out, int out_size, void* d_ws, size_t ws_size,
                              hipStream_t stream) {
  (void)in_sizes; (void)n_in; (void)out_size; (void)ws_size;
  const float* x  = (const float*)d_in[0];
  const float* h0 = (const float*)d_in[1];
  const float* gk = (const float*)d_in[2];
  const float* gb = (const float*)d_in[3];
  const float* ck = (const float*)d_in[4];
  const float* cb = (const float*)d_in[5];
  const float* nz = (const float*)d_in[6];
  float* out = (float*)d_out;

  float* gxe = (float*)d_ws;                 // 789MB f32 (ws is ~1000MiB)
  unsigned short* wpack  = (unsigned short*)(gxe + GXE_F);
  unsigned short* wxpack = wpack + WPACK_US;

  k0_pack<<<1056, 256, 0, stream>>>(gk, ck, wpack, wxpack);
  k1_gxe<<<dim3(16, T_TOTAL), 256, 0, stream>>>(x, nz, gb, cb, wxpack, gxe);
  k2_rec<<<16, 512, 0, stream>>>(h0, wpack, gxe, out);
}

// Round 5
// 2669.649 us; speedup vs baseline: 1.1164x; 1.1164x over previous
//
#include <hip/hip_runtime.h>
#include <math.h>

#define T_TOTAL   1000
#define BATCH     256
#define NH        256
#define NIN       85

static constexpr float SIGMA_C = 0.15811388300841897f;  // sqrt(2/0.2)*0.05
static constexpr float ALPHA_C = 0.2f;

using half8   = __attribute__((ext_vector_type(8))) _Float16;
using f32x4   = __attribute__((ext_vector_type(4))) float;

// workspace layout
#define GXE_F     ((size_t)(T_TOTAL+1)*16*48*256)   // f32 gxe: [t][R][tau(48)][lane(64)][4] = 789MB
#define WPACK_US  (8u*6u*8u*64u*8u)                 // recurrent-weight B-fragments (f16 bits)
#define WXPACK_US (48u*3u*64u*8u)                   // x-weight B-fragments (K padded 85->96)

__device__ __forceinline__ unsigned short f2h(float f){
  _Float16 h = (_Float16)f;
  return __builtin_bit_cast(unsigned short, h);
}

__device__ __forceinline__ void gload_lds16(const void* g, void* l){
  __builtin_amdgcn_global_load_lds((const __attribute__((address_space(1))) void*)g,
                                   (__attribute__((address_space(3))) void*)l, 16, 0, 0);
}

// ---------------- k0: pack weights into MFMA B-fragment order (f16) ----------------
__global__ void k0_pack(const float* __restrict__ gk, const float* __restrict__ ck,
                        unsigned short* __restrict__ wpack, unsigned short* __restrict__ wxpack){
  int tid = blockIdx.x*256 + threadIdx.x;
  if (tid < (int)WPACK_US) {
    int j = tid & 7, l = (tid >> 3) & 63, kt = (tid >> 9) & 7, wt = tid >> 12;
    int w = wt / 6, tile = wt - 6*w;
    int lrow = l & 15, lquad = l >> 4;
    int k = kt*32 + lquad*8 + j;            // hidden index 0..255
    int tau = 2*w + (tile & 1);             // n-tile 0..15
    int kind = tile >> 1;                   // 0=r, 1=u, 2=c
    float v;
    if (kind == 0)      v = gk[(size_t)(85 + k)*512 + 16*tau + lrow];
    else if (kind == 1) v = gk[(size_t)(85 + k)*512 + 256 + 16*tau + lrow];
    else                v = ck[(size_t)(85 + k)*256 + 16*tau + lrow];
    wpack[tid] = f2h(v);
  } else if (tid < (int)(WPACK_US + WXPACK_US)) {
    int f = tid - (int)WPACK_US;
    int j = f & 7, l = (f >> 3) & 63, r = f >> 9;   // r = tau*3 + kt
    int kt = r % 3, tau = r / 3;
    int lrow = l & 15, lquad = l >> 4;
    int k = kt*32 + lquad*8 + j;            // x index, pad >=85 -> 0
    float v = 0.0f;
    if (k < NIN) {
      if (tau < 32) v = gk[(size_t)k*512 + 16*tau + lrow];
      else          v = ck[(size_t)k*256 + 16*(tau-32) + lrow];
    }
    wxpack[f] = f2h(v);
  }
}

// ---------------- k1: gxe precompute, ONE dispatch over all T ----------------
__global__ __launch_bounds__(256) void k1_gxe(const float* __restrict__ x, const float* __restrict__ nz,
                       const float* __restrict__ gb, const float* __restrict__ cb,
                       const unsigned short* __restrict__ wxpack, float* __restrict__ gxe){
  int R  = blockIdx.x;
  int t  = blockIdx.y;
  int tid = threadIdx.x;
  __shared__ _Float16 xA[16][104];           // 96 K (padded) + 8 pad
  {
    int r = tid >> 4, c0 = tid & 15;
    const float* xrow = x + ((size_t)t*BATCH + 16*R + r)*NIN;
    for (int c = c0; c < 96; c += 16)
      xA[r][c] = (_Float16)(c < NIN ? xrow[c] : 0.0f);
  }
  __syncthreads();
  int l = tid & 63, wv = tid >> 6;
  int lrow = l & 15, lquad = l >> 4;
  const half8* xA8 = (const half8*)xA;       // row stride 104 f16 = 13 half8
  half8 afr[3];
  #pragma unroll
  for (int kt = 0; kt < 3; ++kt)
    afr[kt] = xA8[lrow*13 + kt*4 + lquad];
  const half8* wx8 = (const half8*)wxpack;
  size_t gbase = ((size_t)t*16 + R)*48;
  for (int u = 0; u < 12; ++u) {
    int tau = wv + 4*u;                      // balanced: each wave gets 4 cand tiles
    f32x4 acc;
    if (tau < 32) {
      float b = gb[16*tau + lrow];
      acc = (f32x4){b, b, b, b};
    } else {
      int nc = 16*(tau-32) + lrow;
      float b = cb[nc];
      #pragma unroll
      for (int i = 0; i < 4; ++i)
        acc[i] = fmaf(SIGMA_C, nz[((size_t)t*BATCH + 16*R + lquad*4 + i)*NH + nc], b);
    }
    #pragma unroll
    for (int kt = 0; kt < 3; ++kt)
      acc = __builtin_amdgcn_mfma_f32_16x16x32_f16(afr[kt], wx8[((size_t)tau*3 + kt)*64 + l], acc, 0, 0, 0);
    *(f32x4*)(gxe + ((gbase + tau)*64 + (size_t)l)*4) = acc;
  }
}

// ---------------- k2: ONE persistent recurrent scan over all 1000 steps ----------------
// 16 WGs x 8 waves. WG R owns batch rows [16R,16R+16); wave w owns n-cols [32w,32w+32).
// cand = cx + (r .* h) @ Wc_h + sigma*n  (r applied BEFORE the matmul).
// KEY (this round): the 48 resident weight fragments are PINNED to AGPRs via
// asm "+a" so the allocator cannot rematerialize their loads inside the loop
// (R4: VGPR_Count=128 => weights were re-fetched from L2 every step, and the
// counted vmcnt(10) then drained ~48 L2 loads per step). MFMA srcB reads AGPRs
// directly on gfx950 (unified file), so steady-state cost is zero.
__global__ __launch_bounds__(512, 2) void k2_rec(const float* __restrict__ hin,
                       const unsigned short* __restrict__ wpack,
                       const float* __restrict__ gxe,
                       float* __restrict__ out){
  int R = blockIdx.x;
  int tid = threadIdx.x;
  int l = tid & 63, w = tid >> 6;
  int lrow = l & 15, lquad = l >> 4;

  __shared__ float    gst[8*4*256];          // [w][gate tile q(4)][lane][4] f32, 32KB (DMA dest)
  __shared__ _Float16 hA[16][264];           // h f16  [row][n], stride 264
  __shared__ _Float16 rhA[16][264];          // r.*h f16, same layout

  { // init hA
    int r = tid >> 5, c0 = (tid & 31)*8;
    const float* hrow = hin + ((size_t)(16*R + r))*NH + c0;
    #pragma unroll
    for (int i = 0; i < 8; ++i)
      hA[r][c0+i] = (_Float16)hrow[i];
  }
  float hreg[2][4];                          // h f32, lane-private (rows lquad*4+i, cols 32w+16p+lrow)
  #pragma unroll
  for (int p = 0; p < 2; ++p)
    #pragma unroll
    for (int i = 0; i < 4; ++i)
      hreg[p][i] = hin[(size_t)(16*R + lquad*4 + i)*NH + 32*w + 16*p + lrow];

  // resident weight fragments -> AGPR-pinned (192 regs in the acc bank)
  half8 wf[6][8];
  const half8* wp8 = (const half8*)wpack;
  #pragma unroll
  for (int tile = 0; tile < 6; ++tile)
    #pragma unroll
    for (int kt = 0; kt < 8; ++kt)
      wf[tile][kt] = wp8[((w*6 + tile)*8 + kt)*64 + l];
  #pragma unroll
  for (int tile = 0; tile < 6; ++tile)
    #pragma unroll
    for (int kt = 0; kt < 8; ++kt)
      asm volatile("" : "+a"(wf[tile][kt]));   // pin to AGPRs; forbid remat/reload

  // gate staging: tile q -> tau = 2w + {0,1,16,17}; E tiles tau = 32+2w, 33+2w
  const size_t gstep  = (size_t)16*48*256;   // floats per time step
  const float* gsrc   = gxe + ((size_t)R*48 + 2*w)*256 + (size_t)l*4;   // per-lane DMA src
  const f32x4* gep    = (const f32x4*)gxe + ((size_t)R*48 + 32 + 2*w)*64 + (size_t)l;
  float* lbase = gst + (size_t)w*4*256;                                  // wave-uniform LDS dest
  unsigned sb_addr = (unsigned)(unsigned long long)(const void*)lbase + (unsigned)l*16u;

  // prologue: stage step-0 gates, load E(0); __syncthreads drains everything once
  gload_lds16(gsrc,             lbase);
  gload_lds16(gsrc +  1*256,    lbase + 1*256);
  gload_lds16(gsrc + 16*256,    lbase + 2*256);
  gload_lds16(gsrc + 17*256,    lbase + 3*256);
  f32x4 e0 = gep[0];
  f32x4 e1 = gep[64];
  __syncthreads();

  const half8* hA8  = (const half8*)hA;      // row stride 33 half8
  const half8* rhA8 = (const half8*)rhA;
  float* outp = out + ((size_t)(16*R + lquad*4))*NH + 32*w + lrow;

  for (int t = 0; t < T_TOTAL; ++t) {
    // gate preacts: wait own DMA (counted), read gst, data in regs (asm-only access)
    f32x4 accA[4];
    asm volatile(
      "s_waitcnt vmcnt(10)\n\t"
      "ds_read_b128 %0, %4\n\t"
      "ds_read_b128 %1, %4 offset:1024\n\t"
      "ds_read_b128 %2, %4 offset:2048\n\t"
      "ds_read_b128 %3, %4 offset:3072\n\t"
      "s_waitcnt lgkmcnt(0)"
      : "=&v"(accA[0]), "=&v"(accA[1]), "=&v"(accA[2]), "=&v"(accA[3])
      : "v"(sb_addr) : "memory");
    // stage gates(t+1) into the same wave-private slots (slack row at t=999)
    {
      const float* gs = gsrc + gstep;
      gload_lds16(gs,          lbase);
      gload_lds16(gs +  1*256, lbase + 1*256);
      gload_lds16(gs + 16*256, lbase + 2*256);
      gload_lds16(gs + 17*256, lbase + 3*256);
    }
    gsrc += gstep;
    // phase A: h @ Wg_h  (tiles r0,r1,u0,u1)
    #pragma unroll
    for (int kt = 0; kt < 8; ++kt){
      half8 af = hA8[lrow*33 + kt*4 + lquad];
      #pragma unroll
      for (int tile = 0; tile < 4; ++tile)
        accA[tile] = __builtin_amdgcn_mfma_f32_16x16x32_f16(af, wf[tile][kt], accA[tile], 0, 0, 0);
    }
    // ew1: gates; publish rh = r .* h
    float aug[2][4];
    #pragma unroll
    for (int p = 0; p < 2; ++p){
      int ncol = 32*w + 16*p + lrow;
      #pragma unroll
      for (int i = 0; i < 4; ++i){
        float er = __expf(-accA[p][i]);
        float rg = __builtin_amdgcn_rcpf(1.0f + er);
        float eu = __expf(-accA[2+p][i]);
        aug[p][i] = ALPHA_C * __builtin_amdgcn_rcpf(1.0f + eu);
        rhA[lquad*4+i][ncol] = (_Float16)(rg * hreg[p][i]);
      }
    }
    asm volatile("s_waitcnt lgkmcnt(0)\n\ts_barrier" ::: "memory");  // rhA visible
    // phase B: (r.*h) @ Wc_h  (tiles c0,c1)
    f32x4 accB[2];
    accB[0] = (f32x4){0.f,0.f,0.f,0.f};
    accB[1] = (f32x4){0.f,0.f,0.f,0.f};
    #pragma unroll
    for (int kt = 0; kt < 8; ++kt){
      half8 af = rhA8[lrow*33 + kt*4 + lquad];
      #pragma unroll
      for (int tile = 0; tile < 2; ++tile)
        accB[tile] = __builtin_amdgcn_mfma_f32_16x16x32_f16(af, wf[4+tile][kt], accB[tile], 0, 0, 0);
    }
    // ew2: cand -> tanh -> leaky update; publish new h; 8 out stores (never drained)
    #pragma unroll
    for (int p = 0; p < 2; ++p){
      const f32x4 e = p ? e1 : e0;
      int ncol = 32*w + 16*p + lrow;
      #pragma unroll
      for (int i = 0; i < 4; ++i){
        float cand = accB[p][i] + e[i];
        float e2 = __expf(2.0f*cand);
        float c  = (e2 - 1.0f)*__builtin_amdgcn_rcpf(e2 + 1.0f);
        float hold = hreg[p][i];
        float hnew = fmaf(aug[p][i], c - hold, hold);
        hreg[p][i] = hnew;
        hA[lquad*4+i][ncol] = (_Float16)hnew;
        outp[(size_t)i*NH + (size_t)p*16] = hnew;
      }
    }
    outp += (size_t)BATCH*NH;
    // E(t+1) into regs (after last use of e0/e1; part of the vmcnt(10) count)
    gep += gstep/4;
    e0 = gep[0];
    e1 = gep[64];
    asm volatile("s_waitcnt lgkmcnt(0)\n\ts_barrier" ::: "memory");  // hA visible
  }
}

extern "C" void kernel_launch(void* const* d_in, const int* in_sizes, int n_in,
                              void* d_out, int out_size, void* d_ws, size_t ws_size,
                              hipStream_t stream) {
  (void)in_sizes; (void)n_in; (void)out_size; (void)ws_size;
  const float* x  = (const float*)d_in[0];
  const float* h0 = (const float*)d_in[1];
  const float* gk = (const float*)d_in[2];
  const float* gb = (const float*)d_in[3];
  const float* ck = (const float*)d_in[4];
  const float* cb = (const float*)d_in[5];
  const float* nz = (const float*)d_in[6];
  float* out = (float*)d_out;

  float* gxe = (float*)d_ws;                 // 789MB f32 (ws is ~1000MiB)
  unsigned short* wpack  = (unsigned short*)(gxe + GXE_F);
  unsigned short* wxpack = wpack + WPACK_US;

  k0_pack<<<1056, 256, 0, stream>>>(gk, ck, wpack, wxpack);
  k1_gxe<<<dim3(16, T_TOTAL), 256, 0, stream>>>(x, nz, gb, cb, wxpack, gxe);
  k2_rec<<<16, 512, 0, stream>>>(h0, wpack, gxe, out);
}